// Round 12
// baseline (196.965 us; speedup 1.0000x reference)
//
#include <hip/hip_runtime.h>

#define B_    2
#define S_    8192
#define CIN_  64
#define COUT_ 64
#define K_    15
#define NS_   32

typedef unsigned long long u64;
typedef unsigned int u32;
typedef unsigned short u16;
typedef __attribute__((ext_vector_type(8))) short short8;
typedef __attribute__((ext_vector_type(4))) float f32x4;

union U4S8 { uint4 u; short8 s; };

__device__ __forceinline__ u32 f2bf(float x){            // RNE f32 -> bf16 bits
  u32 u = __float_as_uint(x);
  return (u + 0x7FFFu + ((u >> 16) & 1u)) >> 16;
}

// ---------------- u64 wave-wide bitonic helpers (key = (mapped_d<<13)|idx) ----------------
__device__ __forceinline__ void cx(u64 &k, int j, bool up, int lane){
  u64 o = __shfl_xor(k, j, 64);
  bool lower = (lane & j) == 0;
  bool take = (up == lower) ? (o < k) : (o > k);
  if (take) k = o;
}
__device__ __forceinline__ void sort64(u64 &k, int lane){
  #pragma unroll
  for (int kk = 2; kk <= 64; kk <<= 1){
    #pragma unroll
    for (int j = kk >> 1; j > 0; j >>= 1) cx(k, j, (lane & kk) == 0, lane);
  }
}
__device__ __forceinline__ void merge32(u64 &k, int lane){   // lanes 0..31 carry payload
  #pragma unroll
  for (int j = 16; j > 0; j >>= 1) cx(k, j, true, lane);
}

// ---------------- Kernel A: exact top-32 selection, 2 q/wave, 128-pt chunks ----------------
__global__ __launch_bounds__(256) void kp_select(const float* __restrict__ xyz,
                                                 int* __restrict__ nbr){
  __shared__ u64 buf[4][2][128];           // per-wave per-query candidate buffer, 8 KB

  const int tid = threadIdx.x, w = tid >> 6, lane = tid & 63;
  const int qbase = blockIdx.x * 8 + w * 2;
  const int b = qbase >> 13;
  const float* base = xyz + (size_t)b * S_ * 3;

  float qx[2], qy[2], qz[2], sqq[2];
  #pragma unroll
  for (int i = 0; i < 2; ++i){
    int s = (qbase + i) & (S_ - 1);
    qx[i] = base[s*3]; qy[i] = base[s*3+1]; qz[i] = base[s*3+2];
    sqq[i] = qx[i]*qx[i] + qy[i]*qy[i] + qz[i]*qz[i];
  }

  u64 rkey[2] = {~0ull, ~0ull};            // lanes 0..31: running top-32 ascending
  u32 kmd[2]  = {0xBF800000u, 0xBF800000u};  // threshold init at mapped(R^2)
  int cnt[2]  = {0, 0};

  // 2 points per lane, 1-deep prefetch (xyz L2-resident, 96 KB/batch)
  float ax0 = base[lane*3],       ay0 = base[lane*3+1],       az0 = base[lane*3+2];
  float ax1 = base[(64+lane)*3],  ay1 = base[(64+lane)*3+1],  az1 = base[(64+lane)*3+2];

  for (int ch = 0; ch < 64; ++ch){
    float nx0 = ax0, ny0 = ay0, nz0 = az0;
    float nx1 = ax1, ny1 = ay1, nz1 = az1;
    if (ch < 63){
      int p0 = (ch + 1) * 128 + lane, p1 = p0 + 64;
      nx0 = base[p0*3]; ny0 = base[p0*3+1]; nz0 = base[p0*3+2];
      nx1 = base[p1*3]; ny1 = base[p1*3+1]; nz1 = base[p1*3+2];
    }
    float sqp0 = ax0*ax0 + ay0*ay0 + az0*az0;
    float sqp1 = ax1*ax1 + ay1*ay1 + az1*az1;
    int pidx0 = ch * 128 + lane, pidx1 = pidx0 + 64;

    #pragma unroll
    for (int i = 0; i < 2; ++i){
      #pragma unroll
      for (int h = 0; h < 2; ++h){
        float px = h ? ax1 : ax0, py = h ? ay1 : ay0, pz = h ? az1 : az0;
        float sqp = h ? sqp1 : sqp0;
        int pidx = h ? pidx1 : pidx0;
        float dot = qx[i]*px + qy[i]*py + qz[i]*pz;
        float d = -2.0f * dot; d = d + sqq[i]; d = d + sqp;  // reference formula/order
        u32 md = __float_as_uint(d);
        md ^= (u32)((int)md >> 31) | 0x80000000u;            // monotonic float->uint map
        bool pred = md <= kmd[i];                            // ties pass (safe/conservative)
        u64 m = __ballot(pred);
        if (m){
          int pos = cnt[i] + (int)__popcll(m & ((1ull << lane) - 1ull));
          if (pred) buf[w][i][pos] = ((u64)md << 13) | (u32)pidx;
          cnt[i] += (int)__popcll(m);
          if (cnt[i] >= 64){
            cnt[i] -= 64;
            asm volatile("s_waitcnt lgkmcnt(0)" ::: "memory");
            u64 ck = buf[w][i][cnt[i] + lane];
            sort64(ck, lane);                                // chunk ascending
            u64 rev = __shfl(ck, (31 - lane) & 63, 64);      // best-32 reversed into 0..31
            if (rev < rkey[i]) rkey[i] = rev;                // elementwise min -> bitonic
            merge32(rkey[i], lane);                          // 32 smallest of union
            u64 k31 = __shfl(rkey[i], 31, 64);
            kmd[i] = (u32)(k31 >> 13);
          }
        }
      }
    }
    ax0 = nx0; ay0 = ny0; az0 = nz0;
    ax1 = nx1; ay1 = ny1; az1 = nz1;
  }

  #pragma unroll
  for (int i = 0; i < 2; ++i){
    if (cnt[i] > 0){                               // final partial flush
      asm volatile("s_waitcnt lgkmcnt(0)" ::: "memory");
      u64 ck = (lane < cnt[i]) ? buf[w][i][lane] : ~0ull;
      sort64(ck, lane);
      u64 rev = __shfl(ck, (31 - lane) & 63, 64);
      if (rev < rkey[i]) rkey[i] = rev;
      merge32(rkey[i], lane);
    }
    u32 md  = (u32)(rkey[i] >> 13);
    int idx = (int)(rkey[i] & 8191u);
    int i0  = __shfl(idx, 0, 64);
    int wi  = (md > 0xBF800000u) ? i0 : idx;       // d > RADIUS^2 -> nearest idx
    if (lane < NS_) nbr[(size_t)(qbase + i) * NS_ + lane] = wi;
  }
}

// ---------------- Kernel W: expand W[k][c][o] f32 into bf16 B-fragment order ----------------
__global__ void w_cvt(const float* __restrict__ w, u16* __restrict__ wb){
  int idx = blockIdx.x * 256 + threadIdx.x;        // 65536 total
  int i    = idx & 7;
  int lane = (idx >> 3) & 63;
  int st   = (idx >> 9) & 31;
  int wo   = idx >> 14;
  int kc   = st * 32 + (lane >> 4) * 8 + i;
  int k    = kc & 15, c = kc >> 4;
  int o    = wo * 16 + (lane & 15);
  float v  = (k < K_) ? w[(k * 64 + c) * 64 + o] : 0.0f;
  wb[idx] = (u16)f2bf(v);
}

// ---------------- Kernel F: features f32 -> bf16 (halve gather L2 footprint) ----------------
__global__ void f_cvt(const float* __restrict__ f, u16* __restrict__ fb){
  int i = blockIdx.x * 256 + threadIdx.x;          // 262144 threads x 4 elems
  const float4 v = ((const float4*)f)[i];
  ushort4 r;
  r.x = (u16)f2bf(v.x); r.y = (u16)f2bf(v.y);
  r.z = (u16)f2bf(v.z); r.w = (u16)f2bf(v.w);
  ((ushort4*)fb)[i] = r;
}

// ---------------- Kernel B: VALU aggregation (8 waves, 2 q/wave) + MFMA contraction ----------------
__global__ __launch_bounds__(512, 7) void kp_gather(
    const float* __restrict__ xyz, const u16* __restrict__ fbf,
    const float* __restrict__ kp, const u16* __restrict__ wb,
    const int* __restrict__ nbr, float* __restrict__ outp){
  // A tile: 16 rows (q) x 1024 bf16 (kc') = 32 KB, 16B-granule XOR swizzle (g ^= row)
  __shared__ u32 aggA[16 * 512];
  __shared__ float red[4 * 64 * 4];                // K-half partial C, 4 KB

  const int tid = threadIdx.x, w = tid >> 6, lane = tid & 63;
  const int qbase = blockIdx.x * 16;
  const int b = qbase >> 13;
  const float* bx = xyz + (size_t)b * S_ * 3;
  const u16* fbb = fbf + (size_t)b * S_ * CIN_;

  const int kk = lane & 15;
  float kx = 0.f, ky = 0.f, kz = 0.f;
  if (kk < 15){ kx = kp[kk*3]; ky = kp[kk*3+1]; kz = kp[kk*3+2]; }

  float agg[15];

  auto do_q = [&](int ql){
    const int q = qbase + ql;
    const int s = q & (S_ - 1);
    const float qx = bx[s*3], qy = bx[s*3+1], qz = bx[s*3+2];
    int nl = 0; float nx = 0.f, ny = 0.f, nz = 0.f;
    if (lane < NS_){
      nl = nbr[(size_t)q * NS_ + lane];
      nx = bx[nl*3]; ny = bx[nl*3+1]; nz = bx[nl*3+2];
    }
    const float rx = nx - qx, ry = ny - qy, rz = nz - qz;

    // influences, (j,k)-lane-parallel: lane = ((j&3)<<4)|k
    float infl[8];
    #pragma unroll
    for (int jg = 0; jg < 8; ++jg){
      int jj = jg * 4 + (lane >> 4);
      float ax = __shfl(rx, jj, 64), ay = __shfl(ry, jj, 64), az = __shfl(rz, jj, 64);
      float dx = ax - kx, dy = ay - ky, dz = az - kz;
      float sq = dx*dx + dy*dy + dz*dz;
      sq = fmaxf(sq, 0.0f);
      infl[jg] = fmaxf(1.0f - sqrtf(sq + 1e-8f), 0.0f);   // /(R+1e-8) == /1.0f in f32
    }
    #pragma unroll
    for (int k = 0; k < 15; ++k) agg[k] = 0.0f;

    // 1-deep prefetch of the next 4 neighbor feature rows (bf16)
    int nn[4]; float ff[4];
    #pragma unroll
    for (int t = 0; t < 4; ++t) nn[t] = __shfl(nl, t, 64);
    #pragma unroll
    for (int t = 0; t < 4; ++t)
      ff[t] = __uint_as_float((u32)fbb[(size_t)nn[t] * CIN_ + lane] << 16);

    #pragma unroll
    for (int jg = 0; jg < 8; ++jg){
      float f0 = ff[0], f1 = ff[1], f2 = ff[2], f3 = ff[3];
      if (jg < 7){
        #pragma unroll
        for (int t = 0; t < 4; ++t) nn[t] = __shfl(nl, (jg + 1) * 4 + t, 64);
        #pragma unroll
        for (int t = 0; t < 4; ++t)
          ff[t] = __uint_as_float((u32)fbb[(size_t)nn[t] * CIN_ + lane] << 16);
      }
      u32 iv = __float_as_uint(infl[jg]);
      #pragma unroll
      for (int k = 0; k < 15; ++k){
        float s0 = __uint_as_float(__builtin_amdgcn_readlane(iv, k));
        float s1 = __uint_as_float(__builtin_amdgcn_readlane(iv, 16 + k));
        float s2 = __uint_as_float(__builtin_amdgcn_readlane(iv, 32 + k));
        float s3 = __uint_as_float(__builtin_amdgcn_readlane(iv, 48 + k));
        agg[k] = fmaf(s0, f0, agg[k]);
        agg[k] = fmaf(s1, f1, agg[k]);
        agg[k] = fmaf(s2, f2, agg[k]);
        agg[k] = fmaf(s3, f3, agg[k]);
      }
    }
  };

  // A-row store: lane c owns kc' = c*16 .. c*16+15 (its own agg[0..14] + zero pad)
  auto store_row = [&](int r){
    u32 pd[8];
    #pragma unroll
    for (int j = 0; j < 7; ++j) pd[j] = (f2bf(agg[2*j+1]) << 16) | f2bf(agg[2*j]);
    pd[7] = f2bf(agg[14]);                          // high bf16 = +0 pad
    u32* rp = aggA + r * 512;
    int g0 = (lane * 2)     ^ r;                    // 16B-granule XOR swizzle
    int g1 = (lane * 2 + 1) ^ r;
    uint4 v0; v0.x = pd[0]; v0.y = pd[1]; v0.z = pd[2]; v0.w = pd[3];
    uint4 v1; v1.x = pd[4]; v1.y = pd[5]; v1.z = pd[6]; v1.w = pd[7];
    *(uint4*)(rp + g0 * 4) = v0;
    *(uint4*)(rp + g1 * 4) = v1;
  };

  do_q(w * 2 + 0); store_row(w * 2 + 0);
  do_q(w * 2 + 1); store_row(w * 2 + 1);
  __syncthreads();

  // out[16q x 64o] = A[16 x 1024] @ Wb[1024 x 64]
  // wave w: o-block ob = w&3 (cols ob*16..+15), K-half kh = w>>2 (512 each)
  const int r  = lane & 15;                        // A row / D col-in-tile
  const int kb = lane >> 4;                        // k-block 0..3
  const int ob = w & 3, kh = w >> 2;
  f32x4 acc = {0.f, 0.f, 0.f, 0.f};
  const uint4* wb4 = (const uint4*)wb + (size_t)(ob * 32 + kh * 16) * 64 + lane;
  u32* rp = aggA + r * 512;
  #pragma unroll
  for (int sp = 0; sp < 16; ++sp){
    int st = kh * 16 + sp;
    int gp = (st * 4 + kb) ^ r;
    U4S8 a; a.u = *(const uint4*)(rp + gp * 4);
    U4S8 bfr; bfr.u = wb4[sp * 64];
    acc = __builtin_amdgcn_mfma_f32_16x16x32_bf16(a.s, bfr.s, acc, 0, 0, 0);
  }
  if (kh == 1) *(f32x4*)&red[(ob * 64 + lane) * 4] = acc;
  __syncthreads();
  if (kh == 0){
    const float4 p = *(const float4*)&red[(ob * 64 + lane) * 4];
    #pragma unroll
    for (int j = 0; j < 4; ++j){                   // C/D: col=lane&15, row=(lane>>4)*4+j
      int row = kb * 4 + j;
      outp[(size_t)(qbase + row) * COUT_ + ob * 16 + r] = acc[j] + (&p.x)[j];
    }
  }
}

extern "C" void kernel_launch(void* const* d_in, const int* in_sizes, int n_in,
                              void* d_out, int out_size, void* d_ws, size_t ws_size,
                              hipStream_t stream) {
  const float* xyz  = (const float*)d_in[0];
  const float* feat = (const float*)d_in[1];
  const float* w    = (const float*)d_in[2];
  const float* kp   = (const float*)d_in[3];

  float* out = (float*)d_out;                         // [B*S*3 xyz][B*S*64 out]
  u16*   wb  = (u16*)d_ws;                            // 65536 bf16, frag-ordered
  int*   nbr = (int*)((char*)d_ws + 131072);          // 16384*32 ints (2 MB)
  u16*   fbf = (u16*)((char*)d_ws + 131072 + 2097152); // 1M bf16 features (2 MB)

  hipMemcpyAsync(out, xyz, (size_t)B_ * S_ * 3 * sizeof(float),
                 hipMemcpyDeviceToDevice, stream);

  w_cvt<<<256, 256, 0, stream>>>(w, wb);
  f_cvt<<<1024, 256, 0, stream>>>(feat, fbf);
  kp_select<<<(B_ * S_) / 8, 256, 0, stream>>>(xyz, nbr);
  kp_gather<<<(B_ * S_) / 16, 512, 0, stream>>>(xyz, fbf, kp, wb, nbr,
                                                out + (size_t)B_ * S_ * 3);
}